// Round 7
// baseline (121.975 us; speedup 1.0000x reference)
//
#include <hip/hip_runtime.h>

typedef float vf4 __attribute__((ext_vector_type(4)));

#define LOG2E 1.4426950408889634f
#define TWO_LOG2E 2.8853900817779268f

__device__ __forceinline__ float fexp2(float x) { return __builtin_amdgcn_exp2f(x); }
__device__ __forceinline__ float frcp(float x) { return __builtin_amdgcn_rcpf(x); }

// ---------------------------------------------------------------------------
// Kernel 1: projections, k-split x2, exp folded into epilogue:
// stores exp2(2*log2e * acc_half); scores uses tanh(q+k)=1-2/(Eq*Fk+1).
// 128 threads, tile 64m x 64n, 8m x 4n per thread: 3 b128 LDS per 32 FMA
// (was 2 per 16). Grid (64,4,2)=512 blocks -> 2 blocks/CU, 4 waves/CU.
// Block (0,0,0) zeroes Rsum[2048].
__global__ __launch_bounds__(128) void proj_kernel(
    const float* __restrict__ queries, const float* __restrict__ keyes,
    const float* __restrict__ Wq, const float* __restrict__ Wk,
    float* __restrict__ QpH, float* __restrict__ KpH,
    float* __restrict__ Rsum) {
  __shared__ alignas(16) float At[16 * 68];  // [k][m]
  __shared__ alignas(16) float Bt[16 * 68];  // [k][n]
  const int t = threadIdx.x;
  if (blockIdx.x == 0 && blockIdx.y == 0 && blockIdx.z == 0) {
#pragma unroll
    for (int s = 0; s < 4; ++s)
      *(vf4*)&Rsum[t * 16 + s * 4] = (vf4){0.f, 0.f, 0.f, 0.f};
  }
  const int m0 = blockIdx.x * 64;
  const int n0 = blockIdx.y * 64;
  const int k0 = blockIdx.z * 128;  // k-half
  const bool isQ = (m0 < 2048);
  const float* X = isQ ? queries : keyes;
  const float* W = isQ ? Wq : Wk;
  float* C = (isQ ? QpH : KpH) + blockIdx.z * 524288;
  const int mb = isQ ? m0 : (m0 - 2048);

  const int srow = t >> 1;        // staging row 0..63
  const int skq = (t & 1) * 8;    // staging k-offset
  const int tm = t & 7;           // m = m0 + tm*8 + i
  const int tn = t >> 3;          // n = n0 + tn*4 + j  (0..15)

  float acc[8][4] = {};
  for (int kc = k0; kc < k0 + 128; kc += 16) {
    __syncthreads();
    const float* xs = &X[(mb + srow) * 256 + kc + skq];
    const float* ws = &W[(n0 + srow) * 256 + kc + skq];
    vf4 xa0 = *(const vf4*)xs, xa1 = *(const vf4*)(xs + 4);
    vf4 wb0 = *(const vf4*)ws, wb1 = *(const vf4*)(ws + 4);
#pragma unroll
    for (int c = 0; c < 4; ++c) {
      At[(skq + c) * 68 + srow] = xa0[c];
      At[(skq + 4 + c) * 68 + srow] = xa1[c];
      Bt[(skq + c) * 68 + srow] = wb0[c];
      Bt[(skq + 4 + c) * 68 + srow] = wb1[c];
    }
    __syncthreads();
#pragma unroll
    for (int kk = 0; kk < 16; ++kk) {
      vf4 a0 = *(const vf4*)&At[kk * 68 + tm * 8];
      vf4 a1 = *(const vf4*)&At[kk * 68 + tm * 8 + 4];
      vf4 b4 = *(const vf4*)&Bt[kk * 68 + tn * 4];
#pragma unroll
      for (int i = 0; i < 4; ++i)
#pragma unroll
        for (int j = 0; j < 4; ++j) {
          acc[i][j] += a0[i] * b4[j];
          acc[4 + i][j] += a1[i] * b4[j];
        }
    }
  }
#pragma unroll
  for (int i = 0; i < 8; ++i) {
    vf4 o = {fexp2(acc[i][0] * TWO_LOG2E), fexp2(acc[i][1] * TWO_LOG2E),
             fexp2(acc[i][2] * TWO_LOG2E), fexp2(acc[i][3] * TWO_LOG2E)};
    *(vf4*)&C[(mb + tm * 8 + i) * 256 + n0 + tn * 4] = o;
  }
}

// ---------------------------------------------------------------------------
// Kernel 2 (dominant): scores via precomputed exponentials.  Per thread
// 4i x 2j (tile 64i x 32j) -> 7 LDS instr per 32 rcp: trans-pipe-bound.
// inner: acc += wv * rcp(fma(Eq, Fk, 1)).  score = Swv - 2*acc;
// E = masked ? 1 : exp(score); fused row-sums atomicAdd into Rsum.
// Grid (4,8,8)=256 blocks, 256 thr (1 block/CU, 4 waves).
// XOR-swizzled 32-wide LDS rows: staging and reads conflict-free.
__global__ __launch_bounds__(256) void scores_exp_kernel(
    const float* __restrict__ QpH, const float* __restrict__ KpH,
    const float* __restrict__ Wv, const int* __restrict__ valid_lens,
    float* __restrict__ E, float* __restrict__ Rsum) {
  __shared__ alignas(16) float Qs[64 * 32];  // 8 KB
  __shared__ alignas(16) float Ks[32 * 32];  // 4 KB
  __shared__ alignas(16) float wvs[256];
  const int t = threadIdx.x;
  const int i0 = blockIdx.x * 64;
  const int j0 = blockIdx.y * 32;
  const int b = blockIdx.z;
  const int ti = t & 15;   // i = i0 + ti + 16r
  const int tj = t >> 4;   // j = j0 + tj (+16)

  float Swv;  // sum_h wv[h]
  {
    vf4 w4 = *(const vf4*)&Wv[(t & 63) * 4];
    float sw = w4[0] + w4[1] + w4[2] + w4[3];
#pragma unroll
    for (int off = 1; off < 64; off <<= 1) sw += __shfl_xor(sw, off, 64);
    Swv = sw;
  }
  if (t < 64) *(vf4*)&wvs[t * 4] = *(const vf4*)&Wv[t * 4];

  const int qi = t >> 2;            // Qs staging row 0..63
  const int qg = (t & 3) * 2;       // col-group pair
  const int ki = t >> 3;            // Ks staging row 0..31
  const int kg = t & 7;             // col-group
  const int rxor = ti & 7;          // read swizzle for q rows (ti+16r keeps &7)
  const int kxor = tj & 7;

  float acc[4][2] = {};
  for (int hc = 0; hc < 8; ++hc) {
    __syncthreads();
    {
      const int qoff = (((b << 8) + i0 + qi) << 8) + hc * 32 + qg * 4;
      vf4 q1 = *(const vf4*)&QpH[qoff] * *(const vf4*)&QpH[524288 + qoff];
      vf4 q2 = *(const vf4*)&QpH[qoff + 4] * *(const vf4*)&QpH[524288 + qoff + 4];
      *(vf4*)&Qs[qi * 32 + ((qg ^ (qi & 7)) << 2)] = q1;
      *(vf4*)&Qs[qi * 32 + (((qg + 1) ^ (qi & 7)) << 2)] = q2;
      const int koff = (((b << 8) + j0 + ki) << 8) + hc * 32 + kg * 4;
      vf4 kv = *(const vf4*)&KpH[koff] * *(const vf4*)&KpH[524288 + koff];
      *(vf4*)&Ks[ki * 32 + ((kg ^ (ki & 7)) << 2)] = kv;
    }
    __syncthreads();
#pragma unroll
    for (int hh = 0; hh < 8; ++hh) {
      vf4 wv4 = *(const vf4*)&wvs[hc * 32 + hh * 4];
      vf4 k0 = *(const vf4*)&Ks[tj * 32 + ((hh ^ kxor) << 2)];
      vf4 k1 = *(const vf4*)&Ks[(tj + 16) * 32 + ((hh ^ kxor) << 2)];
      vf4 q[4];
#pragma unroll
      for (int r = 0; r < 4; ++r)
        q[r] = *(const vf4*)&Qs[(ti + 16 * r) * 32 + ((hh ^ rxor) << 2)];
#pragma unroll
      for (int e = 0; e < 4; ++e) {
        const float we = wv4[e];
#pragma unroll
        for (int r = 0; r < 4; ++r) {
          acc[r][0] += we * frcp(__builtin_fmaf(q[r][e], k0[e], 1.0f));
          acc[r][1] += we * frcp(__builtin_fmaf(q[r][e], k1[e], 1.0f));
        }
      }
    }
  }

  const int len = valid_lens[b];
#pragma unroll
  for (int c = 0; c < 2; ++c) {
    const int j = j0 + tj + 16 * c;
    const bool masked = (j >= len);
    float s = 0.f;
#pragma unroll
    for (int r = 0; r < 4; ++r) {
      const float score = Swv - 2.0f * acc[r][c];
      const float ev = masked ? 1.0f : fexp2(score * LOG2E);
      E[(((b << 8) + j) << 8) + i0 + ti + 16 * r] = ev;
      s += ev;
    }
#pragma unroll
    for (int off = 1; off < 16; off <<= 1) s += __shfl_xor(s, off, 64);
    if (ti == 0) atomicAdd(&Rsum[(b << 8) + j], s);
  }
}

// ---------------------------------------------------------------------------
// Kernel 3: out partials. out[b,i,d] = sum_j (E[b,j,i]/Rsum[b,j]) * V[b,j,d].
// 4x4 per thread with b128 on BOTH operands (2 b128 / 16 FMA); j-split x4
// (64 j each) for occupancy: grid (16,4,8)=512 blocks, 256 thr, 8 waves/CU.
__global__ __launch_bounds__(256) void out_part_kernel(
    const float* __restrict__ E, const float* __restrict__ Rsum,
    const float* __restrict__ V, float* __restrict__ O4) {
  __shared__ alignas(16) float As[32 * 68];  // [j][i]
  __shared__ alignas(16) float Bs[32 * 68];  // [j][d]
  const int t = threadIdx.x;
  const int i0 = (blockIdx.x & 3) * 64;
  const int js = blockIdx.x >> 2;
  const int d0 = blockIdx.y * 64;
  const int b = blockIdx.z;
  const int ti = t & 15;   // i = i0 + ti*4 + r
  const int td = t >> 4;   // d = d0 + td*4 + c
  const int sr = t >> 3;   // staging row 0..31
  const int sc8 = (t & 7) * 8;

  float acc[4][4] = {};
  for (int jc = 0; jc < 2; ++jc) {
    const int jb = js * 64 + jc * 32;
    __syncthreads();
    const float rj = frcp(Rsum[(b << 8) + jb + sr]);
    {
      const int eoff = (((b << 8) + jb + sr) << 8) + i0 + sc8;
      vf4 a0 = *(const vf4*)&E[eoff] * rj;
      vf4 a1 = *(const vf4*)&E[eoff + 4] * rj;
      *(vf4*)&As[sr * 68 + sc8] = a0;
      *(vf4*)&As[sr * 68 + sc8 + 4] = a1;
      const int voff = (((b << 8) + jb + sr) << 8) + d0 + sc8;
      *(vf4*)&Bs[sr * 68 + sc8] = *(const vf4*)&V[voff];
      *(vf4*)&Bs[sr * 68 + sc8 + 4] = *(const vf4*)&V[voff + 4];
    }
    __syncthreads();
#pragma unroll
    for (int j = 0; j < 32; ++j) {
      vf4 a4 = *(const vf4*)&As[j * 68 + ti * 4];
      vf4 b4 = *(const vf4*)&Bs[j * 68 + td * 4];
#pragma unroll
      for (int r = 0; r < 4; ++r)
#pragma unroll
        for (int c = 0; c < 4; ++c) acc[r][c] += a4[r] * b4[c];
    }
  }
  float* O = O4 + js * 524288;
#pragma unroll
  for (int r = 0; r < 4; ++r) {
    vf4 o = {acc[r][0], acc[r][1], acc[r][2], acc[r][3]};
    *(vf4*)&O[(((b << 8) + i0 + ti * 4 + r) << 8) + d0 + td * 4] = o;
  }
}

// ---------------------------------------------------------------------------
// Kernel 4: sum the four j-split partials (L2-hot).
__global__ __launch_bounds__(256) void out_sum_kernel(
    const float* __restrict__ O4, float* __restrict__ out) {
  const int idx = (blockIdx.x * 256 + threadIdx.x) * 4;
  vf4 s = *(const vf4*)&O4[idx];
  s += *(const vf4*)&O4[524288 + idx];
  s += *(const vf4*)&O4[2 * 524288 + idx];
  s += *(const vf4*)&O4[3 * 524288 + idx];
  *(vf4*)&out[idx] = s;
}

// ---------------------------------------------------------------------------
extern "C" void kernel_launch(void* const* d_in, const int* in_sizes, int n_in,
                              void* d_out, int out_size, void* d_ws, size_t ws_size,
                              hipStream_t stream) {
  const float* queries = (const float*)d_in[0];
  const float* keyes = (const float*)d_in[1];
  const float* values = (const float*)d_in[2];
  const int* valid_lens = (const int*)d_in[3];
  const float* Wq = (const float*)d_in[4];
  const float* Wk = (const float*)d_in[5];
  const float* Wv = (const float*)d_in[6];
  float* out = (float*)d_out;

  float* QpH = (float*)d_ws;       // 2 x 2 MB (k-half exponentials)
  float* KpH = QpH + 2 * 524288;   // 2 x 2 MB
  float* E = KpH + 2 * 524288;     // 2 MB, [b][j][i]
  float* Rsum = E + 524288;        // 8 KB, [b][j]
  float* O4 = Rsum + 2048;         // 4 x 2 MB (j-split partials)

  proj_kernel<<<dim3(64, 4, 2), 128, 0, stream>>>(queries, keyes, Wq, Wk,
                                                  QpH, KpH, Rsum);
  scores_exp_kernel<<<dim3(4, 8, 8), 256, 0, stream>>>(QpH, KpH, Wv,
                                                       valid_lens, E, Rsum);
  out_part_kernel<<<dim3(16, 4, 8), 256, 0, stream>>>(E, Rsum, values, O4);
  out_sum_kernel<<<512, 256, 0, stream>>>(O4, out);
}

// Round 8
// 111.751 us; speedup vs baseline: 1.0915x; 1.0915x over previous
//
#include <hip/hip_runtime.h>

typedef float vf4 __attribute__((ext_vector_type(4)));

#define LOG2E 1.4426950408889634f
#define TWO_LOG2E 2.8853900817779268f

__device__ __forceinline__ float fexp2(float x) { return __builtin_amdgcn_exp2f(x); }
__device__ __forceinline__ float frcp(float x) { return __builtin_amdgcn_rcpf(x); }

// ---------------------------------------------------------------------------
// Kernel 1: projections, k-split x2 (grid 512 = 2 blocks/CU), with the exp
// FOLDED INTO THE EPILOGUE: stores Ep = exp2(2*log2e * acc_half). Scores then
// needs only products: tanh(q+k) = 1 - 2/(Eq*Fk + 1), Eq = Eq1*Eq2.
// Rows 0..2047 = queries@Wq^T -> QpH, else keyes@Wk^T -> KpH.
// Block (0,0,0) also zeroes Rsum[2048] (consumed by scores' atomics).
// NOTE (R7 lesson): 256 threads / 8 waves per CU here beats the 128-thread
// higher-ILP variant — occupancy for latency hiding dominates at this size.
__global__ __launch_bounds__(256) void proj_kernel(
    const float* __restrict__ queries, const float* __restrict__ keyes,
    const float* __restrict__ Wq, const float* __restrict__ Wk,
    float* __restrict__ QpH, float* __restrict__ KpH,
    float* __restrict__ Rsum) {
  __shared__ alignas(16) float At[16 * 68];  // [k][m]
  __shared__ alignas(16) float Bt[16 * 68];  // [k][n]
  const int t = threadIdx.x;
  if (blockIdx.x == 0 && blockIdx.y == 0 && blockIdx.z == 0) {
    *(vf4*)&Rsum[t * 8] = (vf4){0.f, 0.f, 0.f, 0.f};
    *(vf4*)&Rsum[t * 8 + 4] = (vf4){0.f, 0.f, 0.f, 0.f};
  }
  const int m0 = blockIdx.x * 64;
  const int n0 = blockIdx.y * 64;
  const int k0 = blockIdx.z * 128;  // k-half
  const bool isQ = (m0 < 2048);
  const float* X = isQ ? queries : keyes;
  const float* W = isQ ? Wq : Wk;
  float* C = (isQ ? QpH : KpH) + blockIdx.z * 524288;
  const int mb = isQ ? m0 : (m0 - 2048);

  const int lm = t >> 2;
  const int lq = t & 3;
  const int mm4 = (t & 15) * 4;
  const int nn4 = (t >> 4) * 4;

  float acc[4][4] = {};
  for (int kc = k0; kc < k0 + 128; kc += 16) {
    __syncthreads();
    vf4 xa = *(const vf4*)&X[(mb + lm) * 256 + kc + lq * 4];
    vf4 wb = *(const vf4*)&W[(n0 + lm) * 256 + kc + lq * 4];
#pragma unroll
    for (int c = 0; c < 4; ++c) {
      At[(lq * 4 + c) * 68 + lm] = xa[c];
      Bt[(lq * 4 + c) * 68 + lm] = wb[c];
    }
    __syncthreads();
#pragma unroll
    for (int kk = 0; kk < 16; ++kk) {
      vf4 a4 = *(const vf4*)&At[kk * 68 + mm4];
      vf4 b4 = *(const vf4*)&Bt[kk * 68 + nn4];
#pragma unroll
      for (int i = 0; i < 4; ++i)
#pragma unroll
        for (int j = 0; j < 4; ++j) acc[i][j] += a4[i] * b4[j];
    }
  }
#pragma unroll
  for (int i = 0; i < 4; ++i) {
    vf4 o = {fexp2(acc[i][0] * TWO_LOG2E), fexp2(acc[i][1] * TWO_LOG2E),
             fexp2(acc[i][2] * TWO_LOG2E), fexp2(acc[i][3] * TWO_LOG2E)};
    *(vf4*)&C[(mb + mm4 + i) * 256 + n0 + nn4] = o;
  }
}

// ---------------------------------------------------------------------------
// Kernel 2 (dominant): scores via precomputed exponentials — inner loop is
// acc += wv * rcp(fma(Eq, Fk, 1))  (1 trans + 2 VALU per element).
// score = Swv - 2*acc;  E[b][j][i] = masked ? 1 : exp(score).
// Fused row sums via atomicAdd into Rsum (proj zeroed it); masked rows
// accumulate exactly 256.0 -> uniform 1/256 as the reference.
// Tile 32i x 32j x h=256, grid 8x8x8 = 512 (2 blocks/CU, 8 waves/CU = 2/SIMD
// — R2/R7 lesson: dropping below 2 waves/SIMD exposes LDS latency/barriers).
// Per thread 2i x 2j (+16 halves).  XOR-swizzled LDS tiles: conflict-free;
// wv reads are all-lane broadcasts (free).
__global__ __launch_bounds__(256) void scores_exp_kernel(
    const float* __restrict__ QpH, const float* __restrict__ KpH,
    const float* __restrict__ Wv, const int* __restrict__ valid_lens,
    float* __restrict__ E, float* __restrict__ Rsum) {
  __shared__ alignas(16) float Qs[32 * 32];
  __shared__ alignas(16) float Ks[32 * 32];
  __shared__ alignas(16) float wvs[256];
  const int t = threadIdx.x;
  const int i0 = blockIdx.x * 32;
  const int j0 = blockIdx.y * 32;
  const int b = blockIdx.z;
  const int ti = t & 15;   // i = i0 + ti (+16)
  const int tj = t >> 4;   // j = j0 + tj (+16)

  float Swv;  // sum_h wv[h]
  {
    vf4 w4 = *(const vf4*)&Wv[(t & 63) * 4];
    float sw = w4[0] + w4[1] + w4[2] + w4[3];
#pragma unroll
    for (int off = 1; off < 64; off <<= 1) sw += __shfl_xor(sw, off, 64);
    Swv = sw;
  }
  if (t < 64) *(vf4*)&wvs[t * 4] = *(const vf4*)&Wv[t * 4];

  const int srow = t >> 3;       // staging row 0..31
  const int scg = t & 7;         // staging col-group 0..7
  const int swcol = ((scg ^ (srow & 7)) << 2);
  const int qxor = ti & 7;
  const int kxor = tj & 7;

  float acc[2][2] = {};
  for (int hc = 0; hc < 8; ++hc) {
    __syncthreads();
    const int qoff = (((b << 8) + i0 + srow) << 8) + hc * 32 + scg * 4;
    const int koff = (((b << 8) + j0 + srow) << 8) + hc * 32 + scg * 4;
    vf4 qv = *(const vf4*)&QpH[qoff];
    vf4 qv2 = *(const vf4*)&QpH[524288 + qoff];
    vf4 kv = *(const vf4*)&KpH[koff];
    vf4 kv2 = *(const vf4*)&KpH[524288 + koff];
    *(vf4*)&Qs[srow * 32 + swcol] = qv * qv2;  // product of half-exps
    *(vf4*)&Ks[srow * 32 + swcol] = kv * kv2;
    __syncthreads();
#pragma unroll
    for (int hh = 0; hh < 8; ++hh) {
      vf4 q0 = *(const vf4*)&Qs[ti * 32 + ((hh ^ qxor) << 2)];
      vf4 q1 = *(const vf4*)&Qs[(ti + 16) * 32 + ((hh ^ qxor) << 2)];
      vf4 k0 = *(const vf4*)&Ks[tj * 32 + ((hh ^ kxor) << 2)];
      vf4 k1 = *(const vf4*)&Ks[(tj + 16) * 32 + ((hh ^ kxor) << 2)];
      vf4 wv4 = *(const vf4*)&wvs[hc * 32 + hh * 4];
#pragma unroll
      for (int e = 0; e < 4; ++e) {
        const float we = wv4[e];
        acc[0][0] += we * frcp(__builtin_fmaf(q0[e], k0[e], 1.0f));
        acc[0][1] += we * frcp(__builtin_fmaf(q0[e], k1[e], 1.0f));
        acc[1][0] += we * frcp(__builtin_fmaf(q1[e], k0[e], 1.0f));
        acc[1][1] += we * frcp(__builtin_fmaf(q1[e], k1[e], 1.0f));
      }
    }
  }

  const int len = valid_lens[b];
#pragma unroll
  for (int c = 0; c < 2; ++c) {
    const int j = j0 + tj + 16 * c;
    const bool masked = (j >= len);
    float ev[2];
#pragma unroll
    for (int r = 0; r < 2; ++r) {
      const int i = i0 + ti + 16 * r;
      const float score = Swv - 2.0f * acc[r][c];
      ev[r] = masked ? 1.0f : fexp2(score * LOG2E);
      E[(((b << 8) + j) << 8) + i] = ev[r];
    }
    float s = ev[0] + ev[1];
#pragma unroll
    for (int off = 1; off < 16; off <<= 1) s += __shfl_xor(s, off, 64);
    if (ti == 0) atomicAdd(&Rsum[(b << 8) + j], s);
  }
}

// ---------------------------------------------------------------------------
// Kernel 3: out[b,i,d] = sum_j (E[b,j,i]/Rsum[b,j]) * V[b,j,d]. Both operands
// j-major -> outer-product staging; frcp(Rsum) folded into A staging.
// Tile 32i x 64d, 256 threads (2i x 4d each), grid 8x4x8 = 256 blocks
// -> 4 waves/CU.  (R7's j-split x4 variant regressed: +16 MB HBM round-trip
// and a 4th kernel node cost more than the occupancy gain.)
__global__ __launch_bounds__(256) void out_kernel(
    const float* __restrict__ E, const float* __restrict__ Rsum,
    const float* __restrict__ V, float* __restrict__ out) {
  __shared__ alignas(16) float As[32 * 36];  // [j][i]
  __shared__ alignas(16) float Bs[32 * 68];  // [j][d]
  const int t = threadIdx.x;
  const int i0 = blockIdx.x * 32;
  const int d0 = blockIdx.y * 64;
  const int b = blockIdx.z;
  const int ti = t & 15;   // i = i0 + ti (+16)
  const int td = t >> 4;   // d = d0 + td*4
  const int sr = t >> 3;   // staging row 0..31
  const int sc4 = (t & 7) * 4;

  float acc[2][4] = {};
  for (int jc = 0; jc < 8; ++jc) {
    const int jb = jc * 32;
    __syncthreads();
    const float rj = frcp(Rsum[(b << 8) + jb + sr]);
    {
      vf4 a = *(const vf4*)&E[(((b << 8) + jb + sr) << 8) + i0 + sc4];
      *(vf4*)&As[sr * 36 + sc4] = a * rj;
    }
#pragma unroll
    for (int s = 0; s < 2; ++s) {
      const int col = sc4 + s * 32;
      *(vf4*)&Bs[sr * 68 + col] =
          *(const vf4*)&V[(((b << 8) + jb + sr) << 8) + d0 + col];
    }
    __syncthreads();
#pragma unroll
    for (int j = 0; j < 32; ++j) {
      const float a0 = As[j * 36 + ti];
      const float a1 = As[j * 36 + ti + 16];
      vf4 b4 = *(const vf4*)&Bs[j * 68 + td * 4];
#pragma unroll
      for (int c = 0; c < 4; ++c) {
        acc[0][c] += a0 * b4[c];
        acc[1][c] += a1 * b4[c];
      }
    }
  }
#pragma unroll
  for (int r = 0; r < 2; ++r) {
    vf4 o = {acc[r][0], acc[r][1], acc[r][2], acc[r][3]};
    *(vf4*)&out[(((b << 8) + i0 + ti + 16 * r) << 8) + d0 + td * 4] = o;
  }
}

// ---------------------------------------------------------------------------
extern "C" void kernel_launch(void* const* d_in, const int* in_sizes, int n_in,
                              void* d_out, int out_size, void* d_ws, size_t ws_size,
                              hipStream_t stream) {
  const float* queries = (const float*)d_in[0];
  const float* keyes = (const float*)d_in[1];
  const float* values = (const float*)d_in[2];
  const int* valid_lens = (const int*)d_in[3];
  const float* Wq = (const float*)d_in[4];
  const float* Wk = (const float*)d_in[5];
  const float* Wv = (const float*)d_in[6];
  float* out = (float*)d_out;

  float* QpH = (float*)d_ws;       // 2 x 2 MB (k-half exponentials)
  float* KpH = QpH + 2 * 524288;   // 2 x 2 MB
  float* E = KpH + 2 * 524288;     // 2 MB, [b][j][i]
  float* Rsum = E + 524288;        // 8 KB, [b][j]

  proj_kernel<<<dim3(64, 4, 2), 256, 0, stream>>>(queries, keyes, Wq, Wk,
                                                  QpH, KpH, Rsum);
  scores_exp_kernel<<<dim3(8, 8, 8), 256, 0, stream>>>(QpH, KpH, Wv,
                                                       valid_lens, E, Rsum);
  out_kernel<<<dim3(8, 4, 8), 256, 0, stream>>>(E, Rsum, values, out);
}